// Round 1
// baseline (374.219 us; speedup 1.0000x reference)
//
#include <hip/hip_runtime.h>
#include <stdint.h>

#define NTOK 2048
#define DIM  1024
#define HID  2048
#define NEXP 8
#define CAP  4224   // 4096 assignments + 128 tile-overflow pad
#define RB   256    // router blocks

typedef __attribute__((ext_vector_type(8))) short short8;
typedef __attribute__((ext_vector_type(4))) float floatx4;
typedef __attribute__((ext_vector_type(4))) unsigned short ushortx4;
typedef __attribute__((ext_vector_type(8))) unsigned short ushortx8;

static __device__ __forceinline__ unsigned short f2bf(float f) {
  uint32_t u = __builtin_bit_cast(uint32_t, f);
  u += 0x7fffu + ((u >> 16) & 1u);   // round-to-nearest-even
  return (unsigned short)(u >> 16);
}

// ---------------- router (fp32 exact) ----------------
// Weight fp32->bf16 pre-convert pass is GONE: it ran at 20% HBM peak
// (33% occupancy, dispatch-turnover-limited, both streaming and batched
// shapes plateau ~2 TB/s effective). Conversion is now fused into the
// GEMM B-staging (reg-staged), which reads the fp32 weights directly.
__global__ void __launch_bounds__(256) router_kernel(const float* __restrict__ x,
                                                     const float* __restrict__ Wr,
                                                     int* __restrict__ ctrl,
                                                     int* __restrict__ experts,
                                                     float* __restrict__ wts) {
  const int wave = threadIdx.x >> 6;
  const int lane = threadIdx.x & 63;

#pragma unroll
  for (int j = 0; j < 2; j++) {
    int t = blockIdx.x * 8 + wave * 2 + j;
    const float* xr = x + (size_t)t * DIM;
    float acc[NEXP];
#pragma unroll
    for (int e = 0; e < NEXP; e++) acc[e] = 0.f;
#pragma unroll
    for (int i = 0; i < 4; i++) {
      floatx4 v = ((const floatx4*)xr)[i * 64 + lane];
      int idx = (i * 64 + lane) * 4;
#pragma unroll
      for (int e = 0; e < NEXP; e++) {
        floatx4 w = *(const floatx4*)&Wr[e * DIM + idx];
        acc[e] += v.x * w.x + v.y * w.y + v.z * w.z + v.w * w.w;
      }
    }
#pragma unroll
    for (int e = 0; e < NEXP; e++) {
#pragma unroll
      for (int off = 32; off > 0; off >>= 1) acc[e] += __shfl_down(acc[e], off);
    }
    if (lane == 0) {
      float mx = acc[0];
      for (int e = 1; e < NEXP; e++) mx = fmaxf(mx, acc[e]);
      float p[NEXP], s = 0.f;
      for (int e = 0; e < NEXP; e++) { p[e] = expf(acc[e] - mx); s += p[e]; }
      float inv = 1.f / s;
      for (int e = 0; e < NEXP; e++) p[e] *= inv;
      int i0 = 0; float p0 = p[0];
      for (int e = 1; e < NEXP; e++) if (p[e] > p0) { p0 = p[e]; i0 = e; }   // ties: lowest idx
      int i1 = -1; float p1 = -1.f;
      for (int e = 0; e < NEXP; e++) if (e != i0 && p[e] > p1) { p1 = p[e]; i1 = e; }
      float rn = 1.f / (p0 + p1 + 1e-8f);
      experts[2 * t] = i0; experts[2 * t + 1] = i1;
      wts[2 * t] = p0 * rn; wts[2 * t + 1] = p1 * rn;
      atomicAdd(&ctrl[i0], 1);
      atomicAdd(&ctrl[i1], 1);
    }
  }
}

// ---------------- scan: bases + cursors from counts (8 values) ---------------
__global__ void scan_kernel(int* __restrict__ ctrl) {
  if (threadIdx.x == 0) {
    int s = 0;
    for (int e = 0; e < NEXP; e++) { ctrl[8 + e] = s; ctrl[16 + e] = s; s += ctrl[e]; }
  }
}

// ---------------- gather: compact token rows into Xe (bf16) ------------------
__global__ void __launch_bounds__(256) gather_kernel(const float* __restrict__ x,
                                                     int* __restrict__ ctrl,
                                                     const int* __restrict__ experts,
                                                     int* __restrict__ pos,
                                                     unsigned short* __restrict__ Xe) {
  int t = blockIdx.x;
  __shared__ int ps[2];
  if (threadIdx.x == 0) {
    int e0 = experts[2 * t], e1 = experts[2 * t + 1];
    int p0 = atomicAdd(&ctrl[16 + e0], 1);
    int p1 = atomicAdd(&ctrl[16 + e1], 1);
    pos[2 * t] = p0; pos[2 * t + 1] = p1;
    ps[0] = p0; ps[1] = p1;
  }
  __syncthreads();
  int p0 = ps[0], p1 = ps[1];
  int i = threadIdx.x;                         // handles floats 4i..4i+3
  floatx4 v = ((const floatx4*)(x + (size_t)t * DIM))[i];
  ushortx4 b;
  b.x = f2bf(v.x); b.y = f2bf(v.y); b.z = f2bf(v.z); b.w = f2bf(v.w);
  *(ushortx4*)(Xe + (size_t)p0 * DIM + 4 * i) = b;
  *(ushortx4*)(Xe + (size_t)p1 * DIM + 4 * i) = b;
}

// ---------------- m97-style bf16 GEMM, per-expert, fused fp32->bf16 B --------
// A: [CAP x K] bf16 (rows base..) staged via global_load_lds (fast path).
// B: [NEXP*N x K] **fp32** (the original weight tensor) — reg-staged: each
// thread loads 2 float4, converts RNE to bf16, ds_write_b128 into the SAME
// stored-swizzle LDS slot the async path used (reg path writes per-lane, so
// the swizzle is preserved and the LDS-read side is unchanged).
// C = A @ B^T.  EPI=0: relu(C)^2 -> bf16 (He).  EPI=1: fp32 store (Ye).
template <int K, int N, int EPI>
__global__ void __launch_bounds__(256) gemm_kernel(const unsigned short* __restrict__ A,
                                                   const float* __restrict__ B,
                                                   unsigned short* __restrict__ Cbf,
                                                   float* __restrict__ Cf,
                                                   const int* __restrict__ ctrl) {
  const int e = blockIdx.z;
  const int cnt = ctrl[e];
  const int m0 = blockIdx.y * 128;
  if (m0 >= cnt) return;
  const int base = ctrl[8 + e];
  const int n0 = blockIdx.x * 128;

  __shared__ __align__(16) unsigned short ldsA[128 * 64];
  __shared__ __align__(16) unsigned short ldsB[128 * 64];

  const int tid = threadIdx.x;
  const int lane = tid & 63;
  const int wave = tid >> 6;
  const int wm = wave & 1, wn = wave >> 1;

  const unsigned short* Ae = A + (size_t)(base + m0) * K;
  const float* Be = B + ((size_t)e * N + n0) * (size_t)K;

  const int rsub = lane >> 3;   // row within 8-row chunk
  const int sg = lane & 7;      // stored 16B group (swizzled)

  floatx4 acc[4][4];
  floatx4 zero = {0.f, 0.f, 0.f, 0.f};
#pragma unroll
  for (int i = 0; i < 4; i++)
#pragma unroll
    for (int j = 0; j < 4; j++) acc[i][j] = zero;

  for (int k0 = 0; k0 < K; k0 += 64) {
    // issue all global traffic first: 4x A global_load_lds + 8x B float4 loads
    floatx4 b0[4], b1[4];
#pragma unroll
    for (int j = 0; j < 4; j++) {
      int c = wave * 4 + j;
      int rc = c * 8 + rsub;
      int g = sg ^ (rc & 7);
      const unsigned short* ga = Ae + (size_t)rc * K + k0 + g * 8;
      __builtin_amdgcn_global_load_lds((const __attribute__((address_space(1))) unsigned int*)ga,
                                       (__attribute__((address_space(3))) unsigned int*)&ldsA[c * 512],
                                       16, 0, 0);
      const float* gb = Be + (size_t)rc * K + k0 + g * 8;
      b0[j] = ((const floatx4*)gb)[0];
      b1[j] = ((const floatx4*)gb)[1];
    }
    // convert + swizzled LDS write (lane*8 shorts == the async path's dest)
#pragma unroll
    for (int j = 0; j < 4; j++) {
      int c = wave * 4 + j;
      ushortx8 ob;
      ob[0] = f2bf(b0[j].x); ob[1] = f2bf(b0[j].y); ob[2] = f2bf(b0[j].z); ob[3] = f2bf(b0[j].w);
      ob[4] = f2bf(b1[j].x); ob[5] = f2bf(b1[j].y); ob[6] = f2bf(b1[j].z); ob[7] = f2bf(b1[j].w);
      *(ushortx8*)&ldsB[c * 512 + lane * 8] = ob;
    }
    __builtin_amdgcn_s_waitcnt(0x0f70);  // vmcnt(0): A's global_load_lds done
    __syncthreads();                     // compiler drains lgkm for ds_writes

#pragma unroll
    for (int kk = 0; kk < 2; kk++) {
      int q = lane >> 4;
      int gk = kk * 4 + q;
      short8 af[4], bfr[4];
#pragma unroll
      for (int mi = 0; mi < 4; mi++) {
        int row = wm * 64 + mi * 16 + (lane & 15);
        af[mi] = *(const short8*)&ldsA[row * 64 + (gk ^ (row & 7)) * 8];
      }
#pragma unroll
      for (int ni = 0; ni < 4; ni++) {
        int row = wn * 64 + ni * 16 + (lane & 15);
        bfr[ni] = *(const short8*)&ldsB[row * 64 + (gk ^ (row & 7)) * 8];
      }
#pragma unroll
      for (int mi = 0; mi < 4; mi++)
#pragma unroll
        for (int ni = 0; ni < 4; ni++)
          acc[mi][ni] = __builtin_amdgcn_mfma_f32_16x16x32_bf16(af[mi], bfr[ni], acc[mi][ni], 0, 0, 0);
    }
    __syncthreads();
  }

  // epilogue: D row=(lane>>4)*4+reg, col=lane&15
  // expert segments are packed back-to-back: mask stores past cnt.
  const int lm = lane >> 4;
  const int ln = lane & 15;
#pragma unroll
  for (int mi = 0; mi < 4; mi++) {
#pragma unroll
    for (int ni = 0; ni < 4; ni++) {
#pragma unroll
      for (int r = 0; r < 4; r++) {
        int row = m0 + wm * 64 + mi * 16 + lm * 4 + r;   // local row in expert segment
        if (row < cnt) {
          int col = n0 + wn * 64 + ni * 16 + ln;
          float v = acc[mi][ni][r];
          if (EPI == 0) {
            v = fmaxf(v, 0.f);
            v = v * v;
            Cbf[(size_t)(base + row) * N + col] = f2bf(v);
          } else {
            Cf[(size_t)(base + row) * N + col] = v;
          }
        }
      }
    }
  }
}

// ---------------- combine: out[t] = w0*Ye[p0] + w1*Ye[p1] --------------------
__global__ void __launch_bounds__(256) combine_kernel(const float* __restrict__ Ye,
                                                      const int* __restrict__ pos,
                                                      const float* __restrict__ wts,
                                                      float* __restrict__ out) {
  int t = blockIdx.x;
  int i = threadIdx.x;
  int p0 = pos[2 * t], p1 = pos[2 * t + 1];
  float w0 = wts[2 * t], w1 = wts[2 * t + 1];
  floatx4 y0 = ((const floatx4*)(Ye + (size_t)p0 * DIM))[i];
  floatx4 y1 = ((const floatx4*)(Ye + (size_t)p1 * DIM))[i];
  floatx4 o = y0 * w0 + y1 * w1;
  ((floatx4*)(out + (size_t)t * DIM))[i] = o;
  if (t == 0 && i == 0) out[(size_t)NTOK * DIM] = 0.f;  // aux_loss = 0
}

extern "C" void kernel_launch(void* const* d_in, const int* in_sizes, int n_in,
                              void* d_out, int out_size, void* d_ws, size_t ws_size,
                              hipStream_t stream) {
  const float* x   = (const float*)d_in[0];
  const float* Wr  = (const float*)d_in[1];
  const float* Wfc = (const float*)d_in[2];
  const float* Wpr = (const float*)d_in[3];
  float* out = (float*)d_out;
  char* ws = (char*)d_ws;

  int*   ctrl    = (int*)ws;                          // counts[8] bases[8] cursor[8]
  int*   experts = (int*)(ws + 128);                  // int2 per token
  int*   pos     = (int*)(ws + 128 + 16384);          // int2 per token
  float* wts     = (float*)(ws + 128 + 32768);        // float2 per token
  unsigned short* Xe = (unsigned short*)(ws + 65536); // [CAP x DIM] bf16
  unsigned short* He = Xe + (size_t)CAP * DIM;        // [CAP x HID] bf16
  float*          Ye = (float*)(He + (size_t)CAP * HID);  // [CAP x DIM] f32

  hipMemsetAsync(ws, 0, 128, stream);  // zero counts/bases/cursors

  router_kernel<<<RB, 256, 0, stream>>>(x, Wr, ctrl, experts, wts);
  scan_kernel<<<1, 64, 0, stream>>>(ctrl);
  gather_kernel<<<NTOK, 256, 0, stream>>>(x, ctrl, experts, pos, Xe);

  gemm_kernel<DIM, HID, 0><<<dim3(HID / 128, 16, NEXP), 256, 0, stream>>>(Xe, Wfc, He, nullptr, ctrl);
  gemm_kernel<HID, DIM, 1><<<dim3(DIM / 128, 16, NEXP), 256, 0, stream>>>(He, Wpr, nullptr, Ye, ctrl);

  combine_kernel<<<NTOK, 256, 0, stream>>>(Ye, pos, wts, out);
}

// Round 2
// 334.727 us; speedup vs baseline: 1.1180x; 1.1180x over previous
//
#include <hip/hip_runtime.h>
#include <stdint.h>

#define NTOK 2048
#define DIM  1024
#define HID  2048
#define NEXP 8
#define CAP  4224   // 4096 assignments + 128 tile-overflow pad
#define RB   256    // router blocks

typedef __attribute__((ext_vector_type(8))) short short8;
typedef __attribute__((ext_vector_type(4))) float floatx4;
typedef __attribute__((ext_vector_type(4))) unsigned short ushortx4;
typedef __attribute__((ext_vector_type(8))) unsigned short ushortx8;

static __device__ __forceinline__ unsigned short f2bf(float f) {
  uint32_t u = __builtin_bit_cast(uint32_t, f);
  u += 0x7fffu + ((u >> 16) & 1u);   // round-to-nearest-even
  return (unsigned short)(u >> 16);
}

// ---------------- router (fp32 exact, no atomics) ----------------
__global__ void __launch_bounds__(256) router_kernel(const float* __restrict__ x,
                                                     const float* __restrict__ Wr,
                                                     int* __restrict__ experts,
                                                     float* __restrict__ wts) {
  const int wave = threadIdx.x >> 6;
  const int lane = threadIdx.x & 63;

#pragma unroll
  for (int j = 0; j < 2; j++) {
    int t = blockIdx.x * 8 + wave * 2 + j;
    const float* xr = x + (size_t)t * DIM;
    float acc[NEXP];
#pragma unroll
    for (int e = 0; e < NEXP; e++) acc[e] = 0.f;
#pragma unroll
    for (int i = 0; i < 4; i++) {
      floatx4 v = ((const floatx4*)xr)[i * 64 + lane];
      int idx = (i * 64 + lane) * 4;
#pragma unroll
      for (int e = 0; e < NEXP; e++) {
        floatx4 w = *(const floatx4*)&Wr[e * DIM + idx];
        acc[e] += v.x * w.x + v.y * w.y + v.z * w.z + v.w * w.w;
      }
    }
#pragma unroll
    for (int e = 0; e < NEXP; e++) {
#pragma unroll
      for (int off = 32; off > 0; off >>= 1) acc[e] += __shfl_down(acc[e], off);
    }
    if (lane == 0) {
      float mx = acc[0];
      for (int e = 1; e < NEXP; e++) mx = fmaxf(mx, acc[e]);
      float p[NEXP], s = 0.f;
      for (int e = 0; e < NEXP; e++) { p[e] = expf(acc[e] - mx); s += p[e]; }
      float inv = 1.f / s;
      for (int e = 0; e < NEXP; e++) p[e] *= inv;
      int i0 = 0; float p0 = p[0];
      for (int e = 1; e < NEXP; e++) if (p[e] > p0) { p0 = p[e]; i0 = e; }   // ties: lowest idx
      int i1 = -1; float p1 = -1.f;
      for (int e = 0; e < NEXP; e++) if (e != i0 && p[e] > p1) { p1 = p[e]; i1 = e; }
      float rn = 1.f / (p0 + p1 + 1e-8f);
      experts[2 * t] = i0; experts[2 * t + 1] = i1;
      wts[2 * t] = p0 * rn; wts[2 * t + 1] = p1 * rn;
    }
  }
}

// ------- scanpos: counts + bases + per-assignment positions, one 64-lane wave.
// Ballot-based: deterministic (index order), no global atomics, replaces the
// old memset + router atomics + scan_kernel + gather cursor atomics (7->6
// dispatches total).
__global__ void scanpos_kernel(const int* __restrict__ experts,
                               int* __restrict__ ctrl,
                               int* __restrict__ pos) {
  int lane = threadIdx.x;
  if (lane >= 64) return;
  int cnt[NEXP];
#pragma unroll
  for (int e = 0; e < NEXP; e++) cnt[e] = 0;
#pragma unroll 4
  for (int c = 0; c < 2 * NTOK / 64; c++) {
    int v = experts[c * 64 + lane];
#pragma unroll
    for (int e = 0; e < NEXP; e++) cnt[e] += __popcll(__ballot(v == e));
  }
  int basev[NEXP], s = 0;
#pragma unroll
  for (int e = 0; e < NEXP; e++) { basev[e] = s; s += cnt[e]; }
  if (lane < NEXP) { ctrl[lane] = cnt[lane]; ctrl[8 + lane] = basev[lane]; }
  int cur[NEXP];
#pragma unroll
  for (int e = 0; e < NEXP; e++) cur[e] = basev[e];
  unsigned long long below = (1ull << lane) - 1ull;   // lane <= 63, no UB
#pragma unroll 4
  for (int c = 0; c < 2 * NTOK / 64; c++) {
    int v = experts[c * 64 + lane];
    int p = 0;
#pragma unroll
    for (int e = 0; e < NEXP; e++) {
      unsigned long long m = __ballot(v == e);
      if (v == e) p = cur[e] + __popcll(m & below);
      cur[e] += __popcll(m);
    }
    pos[c * 64 + lane] = p;
  }
}

// ---------------- gather: compact token rows into Xe (bf16), no atomics ------
__global__ void __launch_bounds__(256) gather_kernel(const float* __restrict__ x,
                                                     const int* __restrict__ pos,
                                                     unsigned short* __restrict__ Xe) {
  int t = blockIdx.x;
  int p0 = pos[2 * t], p1 = pos[2 * t + 1];   // blockIdx-uniform -> scalar loads
  int i = threadIdx.x;                         // handles floats 4i..4i+3
  floatx4 v = ((const floatx4*)(x + (size_t)t * DIM))[i];
  ushortx4 b;
  b.x = f2bf(v.x); b.y = f2bf(v.y); b.z = f2bf(v.z); b.w = f2bf(v.w);
  *(ushortx4*)(Xe + (size_t)p0 * DIM + 4 * i) = b;
  *(ushortx4*)(Xe + (size_t)p1 * DIM + 4 * i) = b;
}

// ---------------- double-buffered bf16 GEMM, fused fp32->bf16 B --------------
// Per iteration: issue(k+1) -> compute(k) -> convert+ds_write(k+1) -> barrier.
// B's fp32 load latency hides under compute via the register data dependency;
// A's global_load_lds drains at the compiler's pre-barrier vmcnt(0), which now
// sits AFTER the MFMA phase instead of before it (T14 / 2-phase template).
// C = A @ B^T.  EPI=0: relu(C)^2 -> bf16 (He).  EPI=1: fp32 store (Ye).
template <int K, int N, int EPI>
__global__ void __launch_bounds__(256) gemm_kernel(const unsigned short* __restrict__ A,
                                                   const float* __restrict__ B,
                                                   unsigned short* __restrict__ Cbf,
                                                   float* __restrict__ Cf,
                                                   const int* __restrict__ ctrl) {
  const int e = blockIdx.z;
  const int cnt = ctrl[e];
  const int m0 = blockIdx.y * 128;
  if (m0 >= cnt) return;
  const int base = ctrl[8 + e];
  const int n0 = blockIdx.x * 128;

  __shared__ __align__(16) unsigned short ldsA[2][128 * 64];
  __shared__ __align__(16) unsigned short ldsB[2][128 * 64];

  const int tid = threadIdx.x;
  const int lane = tid & 63;
  const int wave = tid >> 6;
  const int wm = wave & 1, wn = wave >> 1;

  const unsigned short* Ae = A + (size_t)(base + m0) * K;
  const float* Be = B + ((size_t)e * N + n0) * (size_t)K;

  const int rsub = lane >> 3;   // row within 8-row chunk
  const int sg = lane & 7;      // stored 16B group (swizzled)

  floatx4 acc[4][4];
  floatx4 zero = {0.f, 0.f, 0.f, 0.f};
#pragma unroll
  for (int i = 0; i < 4; i++)
#pragma unroll
    for (int j = 0; j < 4; j++) acc[i][j] = zero;

  floatx4 rb0[4], rb1[4];   // B staging regs, live across compute

#define STAGE_A(k0, buf)                                                                        \
  _Pragma("unroll")                                                                             \
  for (int j = 0; j < 4; j++) {                                                                 \
    int c = wave * 4 + j;                                                                       \
    int rc = c * 8 + rsub;                                                                      \
    int g = sg ^ (rc & 7);                                                                      \
    const unsigned short* ga = Ae + (size_t)rc * K + (k0) + g * 8;                              \
    __builtin_amdgcn_global_load_lds((const __attribute__((address_space(1))) unsigned int*)ga, \
                                     (__attribute__((address_space(3))) unsigned int*)&ldsA[buf][c * 512], \
                                     16, 0, 0);                                                 \
  }

#define LOAD_B(k0)                                                                              \
  _Pragma("unroll")                                                                             \
  for (int j = 0; j < 4; j++) {                                                                 \
    int rc = (wave * 4 + j) * 8 + rsub;                                                         \
    int g = sg ^ (rc & 7);                                                                      \
    const float* gb = Be + (size_t)rc * K + (k0) + g * 8;                                       \
    rb0[j] = ((const floatx4*)gb)[0];                                                           \
    rb1[j] = ((const floatx4*)gb)[1];                                                           \
  }

#define WRITE_B(buf)                                                                            \
  _Pragma("unroll")                                                                             \
  for (int j = 0; j < 4; j++) {                                                                 \
    int c = wave * 4 + j;                                                                       \
    ushortx8 ob;                                                                                \
    ob[0] = f2bf(rb0[j].x); ob[1] = f2bf(rb0[j].y); ob[2] = f2bf(rb0[j].z); ob[3] = f2bf(rb0[j].w); \
    ob[4] = f2bf(rb1[j].x); ob[5] = f2bf(rb1[j].y); ob[6] = f2bf(rb1[j].z); ob[7] = f2bf(rb1[j].w); \
    *(ushortx8*)&ldsB[buf][c * 512 + lane * 8] = ob;                                            \
  }

#define COMPUTE(buf)                                                                            \
  _Pragma("unroll")                                                                             \
  for (int kk = 0; kk < 2; kk++) {                                                              \
    int gk = kk * 4 + (lane >> 4);                                                              \
    short8 af[4], bfr[4];                                                                       \
    _Pragma("unroll")                                                                           \
    for (int mi = 0; mi < 4; mi++) {                                                            \
      int row = wm * 64 + mi * 16 + (lane & 15);                                                \
      af[mi] = *(const short8*)&ldsA[buf][row * 64 + (gk ^ (row & 7)) * 8];                     \
    }                                                                                           \
    _Pragma("unroll")                                                                           \
    for (int ni = 0; ni < 4; ni++) {                                                            \
      int row = wn * 64 + ni * 16 + (lane & 15);                                                \
      bfr[ni] = *(const short8*)&ldsB[buf][row * 64 + (gk ^ (row & 7)) * 8];                    \
    }                                                                                           \
    _Pragma("unroll")                                                                           \
    for (int mi = 0; mi < 4; mi++)                                                              \
      _Pragma("unroll")                                                                         \
      for (int ni = 0; ni < 4; ni++)                                                            \
        acc[mi][ni] = __builtin_amdgcn_mfma_f32_16x16x32_bf16(af[mi], bfr[ni], acc[mi][ni], 0, 0, 0); \
  }

  // prologue: stage tile 0 into buf 0
  STAGE_A(0, 0)
  LOAD_B(0)
  WRITE_B(0)            // implicit vmcnt wait via rb data dep
  __syncthreads();      // drains A's global_load_lds + ds_writes

  int cur = 0;
  for (int k0 = 64; k0 < K; k0 += 64) {
    int nxt = cur ^ 1;
    STAGE_A(k0, nxt)    // issue next A -> LDS[nxt] (no reg consumer; drains at barrier)
    LOAD_B(k0)          // issue next B -> regs
    COMPUTE(cur)        // MFMA phase covers the load latency
    WRITE_B(nxt)        // stalls only on what latency remains
    __syncthreads();
    cur = nxt;
  }
  COMPUTE(cur)

  // epilogue: D row=(lane>>4)*4+reg, col=lane&15; mask stores past cnt.
  const int lm = lane >> 4;
  const int ln = lane & 15;
#pragma unroll
  for (int mi = 0; mi < 4; mi++) {
#pragma unroll
    for (int ni = 0; ni < 4; ni++) {
#pragma unroll
      for (int r = 0; r < 4; r++) {
        int row = m0 + wm * 64 + mi * 16 + lm * 4 + r;   // local row in expert segment
        if (row < cnt) {
          int col = n0 + wn * 64 + ni * 16 + ln;
          float v = acc[mi][ni][r];
          if (EPI == 0) {
            v = fmaxf(v, 0.f);
            v = v * v;
            Cbf[(size_t)(base + row) * N + col] = f2bf(v);
          } else {
            Cf[(size_t)(base + row) * N + col] = v;
          }
        }
      }
    }
  }
#undef STAGE_A
#undef LOAD_B
#undef WRITE_B
#undef COMPUTE
}

// ---------------- combine: out[t] = w0*Ye[p0] + w1*Ye[p1] --------------------
__global__ void __launch_bounds__(256) combine_kernel(const float* __restrict__ Ye,
                                                      const int* __restrict__ pos,
                                                      const float* __restrict__ wts,
                                                      float* __restrict__ out) {
  int t = blockIdx.x;
  int i = threadIdx.x;
  int p0 = pos[2 * t], p1 = pos[2 * t + 1];
  float w0 = wts[2 * t], w1 = wts[2 * t + 1];
  floatx4 y0 = ((const floatx4*)(Ye + (size_t)p0 * DIM))[i];
  floatx4 y1 = ((const floatx4*)(Ye + (size_t)p1 * DIM))[i];
  floatx4 o = y0 * w0 + y1 * w1;
  ((floatx4*)(out + (size_t)t * DIM))[i] = o;
  if (t == 0 && i == 0) out[(size_t)NTOK * DIM] = 0.f;  // aux_loss = 0
}

extern "C" void kernel_launch(void* const* d_in, const int* in_sizes, int n_in,
                              void* d_out, int out_size, void* d_ws, size_t ws_size,
                              hipStream_t stream) {
  const float* x   = (const float*)d_in[0];
  const float* Wr  = (const float*)d_in[1];
  const float* Wfc = (const float*)d_in[2];
  const float* Wpr = (const float*)d_in[3];
  float* out = (float*)d_out;
  char* ws = (char*)d_ws;

  int*   ctrl    = (int*)ws;                          // counts[8] bases[8]
  int*   experts = (int*)(ws + 128);                  // int2 per token
  int*   pos     = (int*)(ws + 128 + 16384);          // int2 per token
  float* wts     = (float*)(ws + 128 + 32768);        // float2 per token
  unsigned short* Xe = (unsigned short*)(ws + 65536); // [CAP x DIM] bf16
  unsigned short* He = Xe + (size_t)CAP * DIM;        // [CAP x HID] bf16
  float*          Ye = (float*)(He + (size_t)CAP * HID);  // [CAP x DIM] f32

  router_kernel<<<RB, 256, 0, stream>>>(x, Wr, experts, wts);
  scanpos_kernel<<<1, 64, 0, stream>>>(experts, ctrl, pos);
  gather_kernel<<<NTOK, 256, 0, stream>>>(x, pos, Xe);

  gemm_kernel<DIM, HID, 0><<<dim3(HID / 128, 16, NEXP), 256, 0, stream>>>(Xe, Wfc, He, nullptr, ctrl);
  gemm_kernel<HID, DIM, 1><<<dim3(DIM / 128, 16, NEXP), 256, 0, stream>>>(He, Wpr, nullptr, Ye, ctrl);

  combine_kernel<<<NTOK, 256, 0, stream>>>(Ye, pos, wts, out);
}

// Round 3
// 298.958 us; speedup vs baseline: 1.2517x; 1.1196x over previous
//
#include <hip/hip_runtime.h>
#include <stdint.h>

#define NTOK 2048
#define DIM  1024
#define HID  2048
#define NEXP 8
#define CAP  4224   // 4096 assignments + 128 tile-overflow pad
#define RB   256    // router blocks

typedef __attribute__((ext_vector_type(8))) short short8;
typedef __attribute__((ext_vector_type(4))) float floatx4;
typedef __attribute__((ext_vector_type(4))) unsigned short ushortx4;
typedef __attribute__((ext_vector_type(4))) uint32_t uintx4;

static __device__ __forceinline__ unsigned short f2bf(float f) {
  uint32_t u = __builtin_bit_cast(uint32_t, f);
  u += 0x7fffu + ((u >> 16) & 1u);   // round-to-nearest-even
  return (unsigned short)(u >> 16);
}

// ---------------- router (fp32 exact, no atomics) ----------------
__global__ void __launch_bounds__(256) router_kernel(const float* __restrict__ x,
                                                     const float* __restrict__ Wr,
                                                     int* __restrict__ experts,
                                                     float* __restrict__ wts) {
  const int wave = threadIdx.x >> 6;
  const int lane = threadIdx.x & 63;

#pragma unroll
  for (int j = 0; j < 2; j++) {
    int t = blockIdx.x * 8 + wave * 2 + j;
    const float* xr = x + (size_t)t * DIM;
    float acc[NEXP];
#pragma unroll
    for (int e = 0; e < NEXP; e++) acc[e] = 0.f;
#pragma unroll
    for (int i = 0; i < 4; i++) {
      floatx4 v = ((const floatx4*)xr)[i * 64 + lane];
      int idx = (i * 64 + lane) * 4;
#pragma unroll
      for (int e = 0; e < NEXP; e++) {
        floatx4 w = *(const floatx4*)&Wr[e * DIM + idx];
        acc[e] += v.x * w.x + v.y * w.y + v.z * w.z + v.w * w.w;
      }
    }
#pragma unroll
    for (int e = 0; e < NEXP; e++) {
#pragma unroll
      for (int off = 32; off > 0; off >>= 1) acc[e] += __shfl_down(acc[e], off);
    }
    if (lane == 0) {
      float mx = acc[0];
      for (int e = 1; e < NEXP; e++) mx = fmaxf(mx, acc[e]);
      float p[NEXP], s = 0.f;
      for (int e = 0; e < NEXP; e++) { p[e] = expf(acc[e] - mx); s += p[e]; }
      float inv = 1.f / s;
      for (int e = 0; e < NEXP; e++) p[e] *= inv;
      int i0 = 0; float p0 = p[0];
      for (int e = 1; e < NEXP; e++) if (p[e] > p0) { p0 = p[e]; i0 = e; }   // ties: lowest idx
      int i1 = -1; float p1 = -1.f;
      for (int e = 0; e < NEXP; e++) if (e != i0 && p[e] > p1) { p1 = p[e]; i1 = e; }
      float rn = 1.f / (p0 + p1 + 1e-8f);
      experts[2 * t] = i0; experts[2 * t + 1] = i1;
      wts[2 * t] = p0 * rn; wts[2 * t + 1] = p1 * rn;
    }
  }
}

// ------- scanpos: counts + bases + per-assignment positions, one 64-lane wave.
__global__ void scanpos_kernel(const int* __restrict__ experts,
                               int* __restrict__ ctrl,
                               int* __restrict__ pos) {
  int lane = threadIdx.x;
  if (lane >= 64) return;
  int cnt[NEXP];
#pragma unroll
  for (int e = 0; e < NEXP; e++) cnt[e] = 0;
#pragma unroll 4
  for (int c = 0; c < 2 * NTOK / 64; c++) {
    int v = experts[c * 64 + lane];
#pragma unroll
    for (int e = 0; e < NEXP; e++) cnt[e] += __popcll(__ballot(v == e));
  }
  int basev[NEXP], s = 0;
#pragma unroll
  for (int e = 0; e < NEXP; e++) { basev[e] = s; s += cnt[e]; }
  if (lane < NEXP) { ctrl[lane] = cnt[lane]; ctrl[8 + lane] = basev[lane]; }
  int cur[NEXP];
#pragma unroll
  for (int e = 0; e < NEXP; e++) cur[e] = basev[e];
  unsigned long long below = (1ull << lane) - 1ull;
#pragma unroll 4
  for (int c = 0; c < 2 * NTOK / 64; c++) {
    int v = experts[c * 64 + lane];
    int p = 0;
#pragma unroll
    for (int e = 0; e < NEXP; e++) {
      unsigned long long m = __ballot(v == e);
      if (v == e) p = cur[e] + __popcll(m & below);
      cur[e] += __popcll(m);
    }
    pos[c * 64 + lane] = p;
  }
}

// ---------------- gather: compact token rows into Xe (bf16), no atomics ------
__global__ void __launch_bounds__(256) gather_kernel(const float* __restrict__ x,
                                                     const int* __restrict__ pos,
                                                     unsigned short* __restrict__ Xe) {
  int t = blockIdx.x;
  int p0 = pos[2 * t], p1 = pos[2 * t + 1];
  int i = threadIdx.x;
  floatx4 v = ((const floatx4*)(x + (size_t)t * DIM))[i];
  ushortx4 b;
  b.x = f2bf(v.x); b.y = f2bf(v.y); b.z = f2bf(v.z); b.w = f2bf(v.w);
  *(ushortx4*)(Xe + (size_t)p0 * DIM + 4 * i) = b;
  *(ushortx4*)(Xe + (size_t)p1 * DIM + 4 * i) = b;
}

// ---------------- bf16 GEMM, fp32 B staged via global_load_lds ---------------
// Round-0-proven single-buffer loop shape: issue gll -> vmcnt(0) -> barrier ->
// ds_read+MFMA -> barrier. B is the ORIGINAL fp32 weight tensor, DMA'd to LDS
// (pre-swizzled per-lane SOURCE address, linear dest — rule #21), converted to
// bf16 per-fragment at ds_read time with v_cvt_pk_bf16_f32 (RNE, 4 instrs per
// 8 floats — 8x less VALU than round-1's scalar f2bf staging).
// C = A @ B^T.  EPI=0: relu(C)^2 -> bf16 (He).  EPI=1: fp32 store (Ye).
template <int K, int N, int EPI>
__global__ void __launch_bounds__(256) gemm_kernel(const unsigned short* __restrict__ A,
                                                   const float* __restrict__ B,
                                                   unsigned short* __restrict__ Cbf,
                                                   float* __restrict__ Cf,
                                                   const int* __restrict__ ctrl) {
  const int e = blockIdx.z;
  const int cnt = ctrl[e];
  const int m0 = blockIdx.y * 128;
  if (m0 >= cnt) return;
  const int base = ctrl[8 + e];
  const int n0 = blockIdx.x * 128;

  __shared__ __align__(16) unsigned short ldsA[128 * 64];  // 16 KB bf16
  __shared__ __align__(16) float ldsB[128 * 64];           // 32 KB fp32

  const int tid = threadIdx.x;
  const int lane = tid & 63;
  const int wave = tid >> 6;
  const int wm = wave & 1, wn = wave >> 1;

  const unsigned short* Ae = A + (size_t)(base + m0) * K;
  const float* Be = B + ((size_t)e * N + n0) * (size_t)K;

  // A staging: 4 instrs/wave, 8 rows each; 16B bf16 granules, XOR-swizzled src
  const int rsub = lane >> 3;   // row within 8-row chunk
  const int sg = lane & 7;      // 16B granule slot
  // B staging: 8 instrs/wave, 4 rows each; 32B fp32 granules, XOR-swizzled src
  const int br = lane >> 4;     // row within 4-row chunk
  const int bs = lane & 15;     // 16B slot in row (granule = bs>>1, half = bs&1)

  floatx4 acc[4][4];
  floatx4 zero = {0.f, 0.f, 0.f, 0.f};
#pragma unroll
  for (int i = 0; i < 4; i++)
#pragma unroll
    for (int j = 0; j < 4; j++) acc[i][j] = zero;

  for (int k0 = 0; k0 < K; k0 += 64) {
#pragma unroll
    for (int j = 0; j < 4; j++) {
      int c = wave * 4 + j;
      int rc = c * 8 + rsub;
      int g = sg ^ (rc & 7);
      const unsigned short* ga = Ae + (size_t)rc * K + k0 + g * 8;
      __builtin_amdgcn_global_load_lds((const __attribute__((address_space(1))) unsigned int*)ga,
                                       (__attribute__((address_space(3))) unsigned int*)&ldsA[c * 512],
                                       16, 0, 0);
    }
#pragma unroll
    for (int j = 0; j < 8; j++) {
      int R = wave * 32 + j * 4;            // first row of this instr's 4-row group
      int row = R + br;
      int goff = ((bs >> 1) ^ (row & 7)) * 8 + (bs & 1) * 4;   // swizzled fp32 offset
      const float* gb = Be + (size_t)row * K + k0 + goff;
      __builtin_amdgcn_global_load_lds((const __attribute__((address_space(1))) unsigned int*)gb,
                                       (__attribute__((address_space(3))) unsigned int*)&ldsB[R * 64],
                                       16, 0, 0);
    }
    __builtin_amdgcn_s_waitcnt(0x0f70);  // vmcnt(0)
    __syncthreads();

#pragma unroll
    for (int kk = 0; kk < 2; kk++) {
      int gk = kk * 4 + (lane >> 4);
      short8 af[4], bfr[4];
#pragma unroll
      for (int mi = 0; mi < 4; mi++) {
        int row = wm * 64 + mi * 16 + (lane & 15);
        af[mi] = *(const short8*)&ldsA[row * 64 + (gk ^ (row & 7)) * 8];
      }
#pragma unroll
      for (int ni = 0; ni < 4; ni++) {
        int row = wn * 64 + ni * 16 + (lane & 15);
        const float* pb = &ldsB[row * 64 + (gk ^ (row & 7)) * 8];
        floatx4 x0 = ((const floatx4*)pb)[0];
        floatx4 x1 = ((const floatx4*)pb)[1];
        uintx4 uu;
        asm("v_cvt_pk_bf16_f32 %0, %1, %2" : "=v"(uu.x) : "v"(x0.x), "v"(x0.y));
        asm("v_cvt_pk_bf16_f32 %0, %1, %2" : "=v"(uu.y) : "v"(x0.z), "v"(x0.w));
        asm("v_cvt_pk_bf16_f32 %0, %1, %2" : "=v"(uu.z) : "v"(x1.x), "v"(x1.y));
        asm("v_cvt_pk_bf16_f32 %0, %1, %2" : "=v"(uu.w) : "v"(x1.z), "v"(x1.w));
        bfr[ni] = __builtin_bit_cast(short8, uu);
      }
#pragma unroll
      for (int mi = 0; mi < 4; mi++)
#pragma unroll
        for (int ni = 0; ni < 4; ni++)
          acc[mi][ni] = __builtin_amdgcn_mfma_f32_16x16x32_bf16(af[mi], bfr[ni], acc[mi][ni], 0, 0, 0);
    }
    __syncthreads();
  }

  // epilogue: D row=(lane>>4)*4+reg, col=lane&15; mask stores past cnt.
  const int lm = lane >> 4;
  const int ln = lane & 15;
#pragma unroll
  for (int mi = 0; mi < 4; mi++) {
#pragma unroll
    for (int ni = 0; ni < 4; ni++) {
#pragma unroll
      for (int r = 0; r < 4; r++) {
        int row = m0 + wm * 64 + mi * 16 + lm * 4 + r;   // local row in expert segment
        if (row < cnt) {
          int col = n0 + wn * 64 + ni * 16 + ln;
          float v = acc[mi][ni][r];
          if (EPI == 0) {
            v = fmaxf(v, 0.f);
            v = v * v;
            Cbf[(size_t)(base + row) * N + col] = f2bf(v);
          } else {
            Cf[(size_t)(base + row) * N + col] = v;
          }
        }
      }
    }
  }
}

// ---------------- combine: out[t] = w0*Ye[p0] + w1*Ye[p1] --------------------
__global__ void __launch_bounds__(256) combine_kernel(const float* __restrict__ Ye,
                                                      const int* __restrict__ pos,
                                                      const float* __restrict__ wts,
                                                      float* __restrict__ out) {
  int t = blockIdx.x;
  int i = threadIdx.x;
  int p0 = pos[2 * t], p1 = pos[2 * t + 1];
  float w0 = wts[2 * t], w1 = wts[2 * t + 1];
  floatx4 y0 = ((const floatx4*)(Ye + (size_t)p0 * DIM))[i];
  floatx4 y1 = ((const floatx4*)(Ye + (size_t)p1 * DIM))[i];
  floatx4 o = y0 * w0 + y1 * w1;
  ((floatx4*)(out + (size_t)t * DIM))[i] = o;
  if (t == 0 && i == 0) out[(size_t)NTOK * DIM] = 0.f;  // aux_loss = 0
}

extern "C" void kernel_launch(void* const* d_in, const int* in_sizes, int n_in,
                              void* d_out, int out_size, void* d_ws, size_t ws_size,
                              hipStream_t stream) {
  const float* x   = (const float*)d_in[0];
  const float* Wr  = (const float*)d_in[1];
  const float* Wfc = (const float*)d_in[2];
  const float* Wpr = (const float*)d_in[3];
  float* out = (float*)d_out;
  char* ws = (char*)d_ws;

  int*   ctrl    = (int*)ws;                          // counts[8] bases[8]
  int*   experts = (int*)(ws + 128);                  // int2 per token
  int*   pos     = (int*)(ws + 128 + 16384);          // int2 per token
  float* wts     = (float*)(ws + 128 + 32768);        // float2 per token
  unsigned short* Xe = (unsigned short*)(ws + 65536); // [CAP x DIM] bf16
  unsigned short* He = Xe + (size_t)CAP * DIM;        // [CAP x HID] bf16
  float*          Ye = (float*)(He + (size_t)CAP * HID);  // [CAP x DIM] f32

  router_kernel<<<RB, 256, 0, stream>>>(x, Wr, experts, wts);
  scanpos_kernel<<<1, 64, 0, stream>>>(experts, ctrl, pos);
  gather_kernel<<<NTOK, 256, 0, stream>>>(x, pos, Xe);

  gemm_kernel<DIM, HID, 0><<<dim3(HID / 128, 16, NEXP), 256, 0, stream>>>(Xe, Wfc, He, nullptr, ctrl);
  gemm_kernel<HID, DIM, 1><<<dim3(DIM / 128, 16, NEXP), 256, 0, stream>>>(He, Wpr, nullptr, Ye, ctrl);

  combine_kernel<<<NTOK, 256, 0, stream>>>(Ye, pos, wts, out);
}